// Round 17
// baseline (484.774 us; speedup 1.0000x reference)
//
#include <hip/hip_runtime.h>
#include <hip/hip_bf16.h>
#include <float.h>
#include <math.h>

// dims
#define BB   4
#define SS   16
#define TQN  2048
#define DD   768
#define NTT  64
#define NKK  1024     // SS*NTT
#define MID1 204
#define MID2 409

// DIAGNOSTIC amplification (bit-identical output; laundered pointers + asm sinks)
#define MREP 6     // k_mean_u
#define AREP 32    // k_hA inner GEMV
#define OREP 32    // k_oA inner GEMV

typedef float nt_f4 __attribute__((ext_vector_type(4)));

// ---------------------------------------------------------------------------
// K1: U[b,s,q] = sup[b,s,:] . mean_s(reps)[b,q,:]   (amplified x MREP)
// ---------------------------------------------------------------------------
__global__ __launch_bounds__(192) void k_mean_u(const nt_f4* __restrict__ reps,
                                                const float4* __restrict__ sup,
                                                float* __restrict__ U) {
    const int QD4 = TQN * DD / 4;
    int bq = blockIdx.x;
    int b = bq >> 11, q = bq & 2047;
    int t = threadIdx.x;
    const nt_f4* pp = reps + ((size_t)b * SS * TQN + q) * (DD / 4) + t;
    nt_f4 acc = {0.f, 0.f, 0.f, 0.f};
    for (int rep = 0; rep < MREP; ++rep) {
        asm volatile("" : "+v"(pp));          // opaque pointer -> must re-load
        acc = (nt_f4){0.f, 0.f, 0.f, 0.f};
#pragma unroll
        for (int s = 0; s < SS; ++s)
            acc += pp[(size_t)s * QD4];
        asm volatile("" :: "v"(acc.x), "v"(acc.y), "v"(acc.z), "v"(acc.w));
    }
    acc *= (1.f / SS);
    float4 av; av.x = acc.x; av.y = acc.y; av.z = acc.z; av.w = acc.w;

    float part[SS];
#pragma unroll
    for (int s = 0; s < SS; ++s) {
        float4 sv = sup[((size_t)b * SS + s) * (DD / 4) + t];
        part[s] = av.x * sv.x + av.y * sv.y + av.z * sv.z + av.w * sv.w;
    }
    __shared__ float rbuf[3][SS];
    int lane = t & 63, wv = t >> 6;
#pragma unroll
    for (int s = 0; s < SS; ++s) {
        float v = part[s];
        for (int o = 32; o; o >>= 1) v += __shfl_down(v, o, 64);
        if (lane == 0) rbuf[wv][s] = v;
    }
    __syncthreads();
    if (t < SS)
        U[((size_t)b * SS + t) * TQN + q] = rbuf[0][t] + rbuf[1][t] + rbuf[2][t];
}

// ---------------------------------------------------------------------------
// K2: per-(b,s) stats of U over q, and of tgt over n
// ---------------------------------------------------------------------------
__global__ __launch_bounds__(256) void k_stats(const float* __restrict__ U,
                                               const float* __restrict__ tgt,
                                               float* __restrict__ Umax, float* __restrict__ Umin,
                                               float* __restrict__ Usum,
                                               float* __restrict__ cmax, float* __restrict__ cmin,
                                               float* __restrict__ csum) {
    int bs = blockIdx.x, t = threadIdx.x;
    const float* u = U + (size_t)bs * TQN;
    float mx = -FLT_MAX, mn = FLT_MAX, sm = 0.f;
#pragma unroll
    for (int k = 0; k < TQN / 256; ++k) {
        float v = u[t + 256 * k];
        mx = fmaxf(mx, v); mn = fminf(mn, v); sm += v;
    }
    int lane = t & 63, wv = t >> 6;
    for (int o = 32; o; o >>= 1) {
        mx = fmaxf(mx, __shfl_down(mx, o, 64));
        mn = fminf(mn, __shfl_down(mn, o, 64));
        sm += __shfl_down(sm, o, 64);
    }
    __shared__ float smx[4], smn[4], ssm[4];
    if (lane == 0) { smx[wv] = mx; smn[wv] = mn; ssm[wv] = sm; }
    __syncthreads();
    if (t == 0) {
        Umax[bs] = fmaxf(fmaxf(smx[0], smx[1]), fmaxf(smx[2], smx[3]));
        Umin[bs] = fminf(fminf(smn[0], smn[1]), fminf(smn[2], smn[3]));
        Usum[bs] = ssm[0] + ssm[1] + ssm[2] + ssm[3];
    }
    if (wv == 1) {
        float v = tgt[(size_t)bs * NTT + lane];
        float tmx = v, tmn = v, tsm = v;
        for (int o = 32; o; o >>= 1) {
            tmx = fmaxf(tmx, __shfl_down(tmx, o, 64));
            tmn = fminf(tmn, __shfl_down(tmn, o, 64));
            tsm += __shfl_down(tsm, o, 64);
        }
        if (lane == 0) { cmax[bs] = tmx; cmin[bs] = tmn; csum[bs] = tsm; }
    }
}

// ---------------------------------------------------------------------------
// K3: dense feature vectors for both branches
// ---------------------------------------------------------------------------
__global__ __launch_bounds__(256) void k_feat(const float* __restrict__ tgt,
                                              const float* __restrict__ Umax,
                                              const float* __restrict__ Umin,
                                              const float* __restrict__ Usum,
                                              const float* __restrict__ U,
                                              const float* __restrict__ cmax,
                                              const float* __restrict__ cmin,
                                              const float* __restrict__ csum,
                                              float* __restrict__ xm1, float* __restrict__ xa1,
                                              float* __restrict__ xm2, float* __restrict__ xa2) {
    int i = blockIdx.x * 256 + threadIdx.x;
    if (i < BB * NKK) {
        int b = i >> 10, bs = b * SS + ((i & 1023) >> 6);
        float c = tgt[i];
        xm1[i] = c > 0.f ? c * Umax[bs] : (c < 0.f ? c * Umin[bs] : 0.f);
        xa1[i] = c * Usum[bs] * (1.f / TQN);
    } else {
        int i2 = i - BB * NKK;
        if (i2 < BB * TQN) {
            int b = i2 >> 11, q = i2 & 2047;
            float vmax = -FLT_MAX, vsum = 0.f;
#pragma unroll
            for (int s = 0; s < SS; ++s) {
                int bs = b * SS + s;
                float u = U[(size_t)bs * TQN + q];
                float pm_ = u > 0.f ? u * cmax[bs] : (u < 0.f ? u * cmin[bs] : 0.f);
                vmax = fmaxf(vmax, pm_);
                vsum += u * csum[bs];
            }
            xm2[i2] = vmax;
            xa2[i2] = vsum * (1.f / NKK);
        }
    }
}

// ---------------------------------------------------------------------------
// hidden-layer partial body (amplified x AREP inside)
// ---------------------------------------------------------------------------
template<int NH, int JT, int RC>
__device__ __forceinline__ void h_body(int b, int jt, int rc, int t,
                                       const float* __restrict__ xm,
                                       const float* __restrict__ xa,
                                       const float* __restrict__ w1,
                                       float* __restrict__ pm_, float* __restrict__ pa_,
                                       float* sxm, float* sxa) {
    int rbase = rc * 256;
    sxm[t] = xm[rbase + t];
    sxa[t] = xa[rbase + t];
    __syncthreads();
    int lane = t & 63, wv = t >> 6;
    int j = jt * 64 + lane;
    float accm = 0.f, acca = 0.f;
    for (int rep = 0; rep < AREP; ++rep) {
        const float* w1p = w1;
        asm volatile("" : "+v"(w1p));         // defeat cross-rep CSE
        accm = 0.f; acca = 0.f;
        if (j < NH) {
            const float* wp = w1p + (size_t)(rbase + wv * 64) * NH + j;
#pragma unroll
            for (int rr = 0; rr < 64; ++rr) {
                float w = wp[(size_t)rr * NH];
                accm += sxm[wv * 64 + rr] * w;
                acca += sxa[wv * 64 + rr] * w;
            }
        }
        asm volatile("" :: "v"(accm), "v"(acca));
    }
    __shared__ float pm[4][64], pa[4][64];
    pm[wv][lane] = accm; pa[wv][lane] = acca;
    __syncthreads();
    if (t < 64) {
        int idx = ((b * JT + jt) * RC + rc) * 64 + t;
        pm_[idx] = pm[0][t] + pm[1][t] + pm[2][t] + pm[3][t];
        pa_[idx] = pa[0][t] + pa[1][t] + pa[2][t] + pa[3][t];
    }
}

// blocks [0,64): br1 (b, jt<4, rc<4); [64,288): br2 (b, jt<7, rc<8)
__global__ __launch_bounds__(256) void k_hA(const float* __restrict__ xm1,
                                            const float* __restrict__ xa1,
                                            const float* __restrict__ xm2,
                                            const float* __restrict__ xa2,
                                            const float* __restrict__ w1a,
                                            const float* __restrict__ w1b,
                                            float* __restrict__ p1m, float* __restrict__ p1a,
                                            float* __restrict__ p2m, float* __restrict__ p2a) {
    __shared__ float sxm[256], sxa[256];
    int blk = blockIdx.x, t = threadIdx.x;
    if (blk < 64) {
        int b = blk >> 4, jt = (blk >> 2) & 3, rc = blk & 3;
        h_body<MID1, 4, 4>(b, jt, rc, t, xm1 + b * NKK, xa1 + b * NKK, w1a,
                           p1m, p1a, sxm, sxa);
    } else {
        int blk2 = blk - 64;
        int b = blk2 / 56, r_ = blk2 % 56, jt = r_ >> 3, rc = r_ & 7;
        h_body<MID2, 7, 8>(b, jt, rc, t, xm2 + b * TQN, xa2 + b * TQN, w1b,
                           p2m, p2a, sxm, sxa);
    }
}

// ---------------------------------------------------------------------------
// out-layer partial body (amplified x OREP inside)
// ---------------------------------------------------------------------------
template<int NH, int NOUT, int RT, int JC, int CHJ, int JT, int RC>
__device__ __forceinline__ void o_body(int b, int rt, int jc, int t,
                                       const float* __restrict__ pmL,
                                       const float* __restrict__ paL,
                                       const float* __restrict__ b1,
                                       const float* __restrict__ w2,
                                       float* __restrict__ qm_, float* __restrict__ qa_,
                                       float* shm, float* sha) {
    int jbase = jc * CHJ;
    if (t < CHJ) {
        int j = jbase + t;
        if (j < NH) {
            int jt_ = j >> 6, t64 = j & 63;
            float m_ = 0.f, a_ = 0.f;
#pragma unroll
            for (int rc = 0; rc < RC; ++rc) {
                int idx = ((b * JT + jt_) * RC + rc) * 64 + t64;
                m_ += pmL[idx]; a_ += paL[idx];
            }
            float bb_ = b1[j];
            shm[t] = fmaxf(m_ + bb_, 0.f);
            sha[t] = fmaxf(a_ + bb_, 0.f);
        } else { shm[t] = 0.f; sha[t] = 0.f; }
    }
    __syncthreads();
    int rl = t & 127, jp = t >> 7;
    int r = rt * 128 + rl;
    float accm = 0.f, acca = 0.f;
    for (int rep = 0; rep < OREP; ++rep) {
        const float* w2p = w2;
        asm volatile("" : "+v"(w2p));
        accm = 0.f; acca = 0.f;
#pragma unroll 8
        for (int jj = jp; jj < CHJ; jj += 2) {
            int j = jbase + jj;
            int j2 = j < NH ? j : NH - 1;
            float w = w2p[(size_t)j2 * NOUT + r];
            accm += shm[jj] * w; acca += sha[jj] * w;
        }
        asm volatile("" :: "v"(accm), "v"(acca));
    }
    __shared__ float qm[2][128], qa[2][128];
    qm[jp][rl] = accm; qa[jp][rl] = acca;
    __syncthreads();
    if (t < 128) {
        int idx = ((b * RT + rt) * JC + jc) * 128 + t;
        qm_[idx] = qm[0][t] + qm[1][t];
        qa_[idx] = qa[0][t] + qa[1][t];
    }
}

// blocks [0,64): br1 (b, rt<8, jc<2); [64,320): br2 (b, rt<16, jc<4)
__global__ __launch_bounds__(256) void k_oA(const float* __restrict__ p1m,
                                            const float* __restrict__ p1a,
                                            const float* __restrict__ p2m,
                                            const float* __restrict__ p2a,
                                            const float* __restrict__ b1a_,
                                            const float* __restrict__ b1b_,
                                            const float* __restrict__ w2a,
                                            const float* __restrict__ w2b,
                                            float* __restrict__ q1m, float* __restrict__ q1a,
                                            float* __restrict__ q2m, float* __restrict__ q2a) {
    __shared__ float shm[104], sha[104];
    int blk = blockIdx.x, t = threadIdx.x;
    if (blk < 64) {
        int b = blk >> 4, rt = (blk >> 1) & 7, jc = blk & 1;
        o_body<MID1, NKK, 8, 2, 102, 4, 4>(b, rt, jc, t, p1m, p1a, b1a_, w2a,
                                           q1m, q1a, shm, sha);
    } else {
        int blk2 = blk - 64;
        int b = blk2 >> 6, r_ = blk2 & 63, rt = r_ >> 2, jc = r_ & 3;
        o_body<MID2, TQN, 16, 4, 103, 7, 8>(b, rt, jc, t, p2m, p2a, b1b_, w2b,
                                            q2m, q2a, shm, sha);
    }
}

// ---------------------------------------------------------------------------
// K6: finalize out-layer + fuse MLP + softmax + 1.
// ---------------------------------------------------------------------------
__global__ __launch_bounds__(256) void k_smx(const float* __restrict__ q1m,
                                             const float* __restrict__ q1a,
                                             const float* __restrict__ q2m,
                                             const float* __restrict__ q2a,
                                             const float* __restrict__ b2a_,
                                             const float* __restrict__ b2b_,
                                             const float* __restrict__ fw1, const float* __restrict__ fb1,
                                             const float* __restrict__ fw2, const float* __restrict__ fb2,
                                             float* __restrict__ W1, float* __restrict__ W2) {
    int blk = blockIdx.x, t = threadIdx.x;
    int lane = t & 63, wv = t >> 6;
    float f0 = fw1[0], f1 = fw1[1], fb = fb1[0], g0 = fw2[0], gb = fb2[0];
    __shared__ float rb[4];

    if (blk < BB) {
        int b = blk;
        float yv[4];
#pragma unroll
        for (int k = 0; k < 4; ++k) {
            int r = t + 256 * k;
            int rt = r >> 7, rl = r & 127;
            float bb_ = b2a_[r];
            float ym = bb_, ya = bb_;
#pragma unroll
            for (int jc = 0; jc < 2; ++jc) {
                int idx = ((b * 8 + rt) * 2 + jc) * 128 + rl;
                ym += q1m[idx]; ya += q1a[idx];
            }
            float z = fmaxf(ya * f0 + ym * f1 + fb, 0.f);
            yv[k] = z * g0 + gb;
        }
        float mx = fmaxf(fmaxf(yv[0], yv[1]), fmaxf(yv[2], yv[3]));
        for (int o = 32; o; o >>= 1) mx = fmaxf(mx, __shfl_down(mx, o, 64));
        if (lane == 0) rb[wv] = mx;
        __syncthreads();
        mx = fmaxf(fmaxf(rb[0], rb[1]), fmaxf(rb[2], rb[3]));
        __syncthreads();
        float e[4], sm = 0.f;
#pragma unroll
        for (int k = 0; k < 4; ++k) { e[k] = expf(yv[k] - mx); sm += e[k]; }
        for (int o = 32; o; o >>= 1) sm += __shfl_down(sm, o, 64);
        if (lane == 0) rb[wv] = sm;
        __syncthreads();
        sm = rb[0] + rb[1] + rb[2] + rb[3];
        float inv = 1.f / sm;
#pragma unroll
        for (int k = 0; k < 4; ++k)
            W1[b * NKK + t + 256 * k] = e[k] * inv + 1.f;
    } else {
        int b = blk - BB;
        float yv[8];
#pragma unroll
        for (int k = 0; k < 8; ++k) {
            int r = t + 256 * k;
            int rt = r >> 7, rl = r & 127;
            float bb_ = b2b_[r];
            float ym = bb_, ya = bb_;
#pragma unroll
            for (int jc = 0; jc < 4; ++jc) {
                int idx = ((b * 16 + rt) * 4 + jc) * 128 + rl;
                ym += q2m[idx]; ya += q2a[idx];
            }
            float z = fmaxf(ya * f0 + ym * f1 + fb, 0.f);
            yv[k] = z * g0 + gb;
        }
        float mx = yv[0];
#pragma unroll
        for (int k = 1; k < 8; ++k) mx = fmaxf(mx, yv[k]);
        for (int o = 32; o; o >>= 1) mx = fmaxf(mx, __shfl_down(mx, o, 64));
        if (lane == 0) rb[wv] = mx;
        __syncthreads();
        mx = fmaxf(fmaxf(rb[0], rb[1]), fmaxf(rb[2], rb[3]));
        __syncthreads();
        float e[8], sm = 0.f;
#pragma unroll
        for (int k = 0; k < 8; ++k) { e[k] = expf(yv[k] - mx); sm += e[k]; }
        for (int o = 32; o; o >>= 1) sm += __shfl_down(sm, o, 64);
        if (lane == 0) rb[wv] = sm;
        __syncthreads();
        sm = rb[0] + rb[1] + rb[2] + rb[3];
        float inv = 1.f / sm;
#pragma unroll
        for (int k = 0; k < 8; ++k) W2[b * TQN + t + 256 * k] = e[k] * inv + 1.f;
    }
}

// ---------------------------------------------------------------------------
// K7: proto output + c2[b,s,n]
// ---------------------------------------------------------------------------
__global__ __launch_bounds__(256) void k_proto(const float* __restrict__ W1,
                                               const float* __restrict__ tgt,
                                               const float* __restrict__ sup,
                                               float* __restrict__ proto,
                                               float* __restrict__ c2) {
    int bn = blockIdx.x;
    int b = bn >> 6, n = bn & 63;
    int t = threadIdx.x;
    float a0 = 0.f, a1 = 0.f, a2 = 0.f, cnt = 0.f;
#pragma unroll
    for (int s = 0; s < SS; ++s) {
        float tg = tgt[((size_t)b * SS + s) * NTT + n];
        float coef = W1[b * NKK + s * NTT + n] * tg;
        const float* sv = sup + ((size_t)b * SS + s) * DD;
        a0 += coef * sv[t];
        a1 += coef * sv[t + 256];
        a2 += coef * sv[t + 512];
        cnt += tg;
    }
    float inv = 1.f / (cnt + 1e-4f);
    float* p = proto + (size_t)bn * DD;
    p[t] = a0 * inv; p[t + 256] = a1 * inv; p[t + 512] = a2 * inv;
    if (t < SS) {
        float tg = tgt[((size_t)b * SS + t) * NTT + n];
        c2[((size_t)b * SS + t) * NTT + n] = W1[b * NKK + t * NTT + n] * tg * inv;
    }
}

// ---------------------------------------------------------------------------
// K8: sim[b,q,n] = W2[b,q] * sum_s U[b,s,q] * c2[b,s,n]
// ---------------------------------------------------------------------------
__global__ __launch_bounds__(256) void k_simU(const float* __restrict__ U,
                                              const float* __restrict__ c2,
                                              const float* __restrict__ W2,
                                              float* __restrict__ sim) {
    int blk = blockIdx.x;
    int b = blk >> 3, q0 = (blk & 7) * 256;
    int t = threadIdx.x;
    __shared__ float sc[SS][NTT];
    for (int i = t; i < SS * NTT; i += 256)
        sc[i >> 6][i & 63] = c2[(size_t)b * SS * NTT + i];
    __syncthreads();
    int q = q0 + t;
    float u[SS];
#pragma unroll
    for (int s = 0; s < SS; ++s)
        u[s] = U[((size_t)b * SS + s) * TQN + q];
    float w = W2[b * TQN + q];
    float* simp = sim + ((size_t)b * TQN + q) * NTT;
#pragma unroll 4
    for (int n4 = 0; n4 < NTT / 4; ++n4) {
        float4 o;
        float a0 = 0.f, a1 = 0.f, a2 = 0.f, a3 = 0.f;
#pragma unroll
        for (int s = 0; s < SS; ++s) {
            float us = u[s];
            a0 += us * sc[s][n4 * 4 + 0];
            a1 += us * sc[s][n4 * 4 + 1];
            a2 += us * sc[s][n4 * 4 + 2];
            a3 += us * sc[s][n4 * 4 + 3];
        }
        o.x = a0 * w; o.y = a1 * w; o.z = a2 * w; o.w = a3 * w;
        *reinterpret_cast<float4*>(&simp[n4 * 4]) = o;
    }
}

// ---------------------------------------------------------------------------
extern "C" void kernel_launch(void* const* d_in, const int* in_sizes, int n_in,
                              void* d_out, int out_size, void* d_ws, size_t ws_size,
                              hipStream_t stream) {
    const float* reps = (const float*)d_in[0];
    const float* sup  = (const float*)d_in[1];
    const float* tgt  = (const float*)d_in[4];
    const float* l1w1 = (const float*)d_in[5];
    const float* l1b1 = (const float*)d_in[6];
    const float* l1w2 = (const float*)d_in[7];
    const float* l1b2 = (const float*)d_in[8];
    const float* l2w1 = (const float*)d_in[9];
    const float* l2b1 = (const float*)d_in[10];
    const float* l2w2 = (const float*)d_in[11];
    const float* l2b2 = (const float*)d_in[12];
    const float* fw1  = (const float*)d_in[13];
    const float* fb1  = (const float*)d_in[14];
    const float* fw2  = (const float*)d_in[15];
    const float* fb2  = (const float*)d_in[16];

    float* out    = (float*)d_out;
    float* simO   = out;
    float* protoO = out + (size_t)BB * TQN * NTT;

    float* w = (float*)d_ws;
    float* U     = w; w += (size_t)BB * SS * TQN;
    float* Umax  = w; w += 64;
    float* Umin  = w; w += 64;
    float* Usum  = w; w += 64;
    float* cmaxp = w; w += 64;
    float* cminp = w; w += 64;
    float* csump = w; w += 64;
    float* xm1   = w; w += BB * NKK;
    float* xa1   = w; w += BB * NKK;
    float* xm2   = w; w += BB * TQN;
    float* xa2   = w; w += BB * TQN;
    float* p1m   = w; w += BB * 4 * 4 * 64;
    float* p1a   = w; w += BB * 4 * 4 * 64;
    float* p2m   = w; w += BB * 7 * 8 * 64;
    float* p2a   = w; w += BB * 7 * 8 * 64;
    float* q1m   = w; w += BB * 8 * 2 * 128;
    float* q1a   = w; w += BB * 8 * 2 * 128;
    float* q2m   = w; w += BB * 16 * 4 * 128;
    float* q2a   = w; w += BB * 16 * 4 * 128;
    float* W1    = w; w += BB * NKK;
    float* W2    = w; w += BB * TQN;
    float* c2    = w; w += BB * SS * NTT;

    k_mean_u<<<BB * TQN, 192, 0, stream>>>((const nt_f4*)reps, (const float4*)sup, U);
    k_stats<<<BB * SS, 256, 0, stream>>>(U, tgt, Umax, Umin, Usum, cmaxp, cminp, csump);
    k_feat<<<(BB * NKK + BB * TQN) / 256, 256, 0, stream>>>(tgt, Umax, Umin, Usum,
                                                            U, cmaxp, cminp, csump,
                                                            xm1, xa1, xm2, xa2);
    k_hA<<<64 + 224, 256, 0, stream>>>(xm1, xa1, xm2, xa2, l1w1, l2w1,
                                       p1m, p1a, p2m, p2a);
    k_oA<<<64 + 256, 256, 0, stream>>>(p1m, p1a, p2m, p2a, l1b1, l2b1,
                                       l1w2, l2w2, q1m, q1a, q2m, q2a);
    k_smx<<<2 * BB, 256, 0, stream>>>(q1m, q1a, q2m, q2a, l1b2, l2b2,
                                      fw1, fb1, fw2, fb2, W1, W2);
    k_proto<<<BB * NTT, 256, 0, stream>>>(W1, tgt, sup, protoO, c2);
    k_simU<<<BB * (TQN / 256), 256, 0, stream>>>(U, c2, W2, simO);
}

// Round 18
// 122.009 us; speedup vs baseline: 3.9733x; 3.9733x over previous
//
#include <hip/hip_runtime.h>
#include <hip/hip_bf16.h>
#include <float.h>
#include <math.h>

// dims
#define BB   4
#define SS   16
#define TQN  2048
#define DD   768
#define NTT  64
#define NKK  1024     // SS*NTT
#define MID1 204
#define MID2 409

typedef float nt_f4 __attribute__((ext_vector_type(4)));

// ---------------------------------------------------------------------------
// K1 v2: U[b,s,q] = sup[b,s,:] . mean_s'(reps)[b,q,:]
// Block owns 8 consecutive q rows -> each s-slice read is 24 KB contiguous
// (8x longer DRAM streams than v1's 3 KB). Mean lives in registers;
// sup[b] staged in LDS; per-(q,s) dot via 32-lane shuffle reduce.
// ---------------------------------------------------------------------------
__global__ __launch_bounds__(256) void k_mean_u(const nt_f4* __restrict__ reps,
                                                const float4* __restrict__ sup,
                                                float* __restrict__ U) {
    const int QD4 = DD / 4;                    // 192 float4 per row
    int blk = blockIdx.x;                      // [0, BB*TQN/8) = 1024
    int b = blk >> 8, q0 = (blk & 255) * 8;
    int t = threadIdx.x;
    int ql = t >> 5;                           // 0..7  (q = q0+ql)
    int qb = t & 31;                           // base quad

    __shared__ float4 ssup[SS * QD4];          // 48 KB: sup[b] staged once
    for (int i = t; i < SS * QD4; i += 256)
        ssup[i] = sup[(size_t)b * SS * QD4 + i];

    nt_f4 acc[6] = {};
    const nt_f4* base = reps + ((size_t)b * SS * TQN + q0 + ql) * QD4;
    const size_t sstr = (size_t)TQN * QD4;     // s-slice stride
    for (int s = 0; s < SS; ++s) {
        const nt_f4* p = base + (size_t)s * sstr;
#pragma unroll
        for (int k = 0; k < 6; ++k)
            acc[k] += p[qb + 32 * k];
    }
#pragma unroll
    for (int k = 0; k < 6; ++k) acc[k] *= (1.f / SS);
    __syncthreads();

    for (int s = 0; s < SS; ++s) {
        float psum = 0.f;
#pragma unroll
        for (int k = 0; k < 6; ++k) {
            float4 sv = ssup[s * QD4 + qb + 32 * k];   // same addr across q-halves: broadcast
            psum += acc[k].x * sv.x + acc[k].y * sv.y
                  + acc[k].z * sv.z + acc[k].w * sv.w;
        }
        for (int o = 16; o; o >>= 1) psum += __shfl_down(psum, o, 32);
        if (qb == 0)
            U[((size_t)(b * SS + s)) * TQN + q0 + ql] = psum;
    }
}

// ---------------------------------------------------------------------------
// K2: per-(b,s) stats of U over q, and of tgt over n
// ---------------------------------------------------------------------------
__global__ __launch_bounds__(256) void k_stats(const float* __restrict__ U,
                                               const float* __restrict__ tgt,
                                               float* __restrict__ Umax, float* __restrict__ Umin,
                                               float* __restrict__ Usum,
                                               float* __restrict__ cmax, float* __restrict__ cmin,
                                               float* __restrict__ csum) {
    int bs = blockIdx.x, t = threadIdx.x;
    const float* u = U + (size_t)bs * TQN;
    float mx = -FLT_MAX, mn = FLT_MAX, sm = 0.f;
#pragma unroll
    for (int k = 0; k < TQN / 256; ++k) {
        float v = u[t + 256 * k];
        mx = fmaxf(mx, v); mn = fminf(mn, v); sm += v;
    }
    int lane = t & 63, wv = t >> 6;
    for (int o = 32; o; o >>= 1) {
        mx = fmaxf(mx, __shfl_down(mx, o, 64));
        mn = fminf(mn, __shfl_down(mn, o, 64));
        sm += __shfl_down(sm, o, 64);
    }
    __shared__ float smx[4], smn[4], ssm[4];
    if (lane == 0) { smx[wv] = mx; smn[wv] = mn; ssm[wv] = sm; }
    __syncthreads();
    if (t == 0) {
        Umax[bs] = fmaxf(fmaxf(smx[0], smx[1]), fmaxf(smx[2], smx[3]));
        Umin[bs] = fminf(fminf(smn[0], smn[1]), fminf(smn[2], smn[3]));
        Usum[bs] = ssm[0] + ssm[1] + ssm[2] + ssm[3];
    }
    if (wv == 1) {
        float v = tgt[(size_t)bs * NTT + lane];
        float tmx = v, tmn = v, tsm = v;
        for (int o = 32; o; o >>= 1) {
            tmx = fmaxf(tmx, __shfl_down(tmx, o, 64));
            tmn = fminf(tmn, __shfl_down(tmn, o, 64));
            tsm += __shfl_down(tsm, o, 64);
        }
        if (lane == 0) { cmax[bs] = tmx; cmin[bs] = tmn; csum[bs] = tsm; }
    }
}

// ---------------------------------------------------------------------------
// K3: dense feature vectors for both branches
// ---------------------------------------------------------------------------
__global__ __launch_bounds__(256) void k_feat(const float* __restrict__ tgt,
                                              const float* __restrict__ Umax,
                                              const float* __restrict__ Umin,
                                              const float* __restrict__ Usum,
                                              const float* __restrict__ U,
                                              const float* __restrict__ cmax,
                                              const float* __restrict__ cmin,
                                              const float* __restrict__ csum,
                                              float* __restrict__ xm1, float* __restrict__ xa1,
                                              float* __restrict__ xm2, float* __restrict__ xa2) {
    int i = blockIdx.x * 256 + threadIdx.x;
    if (i < BB * NKK) {
        int b = i >> 10, bs = b * SS + ((i & 1023) >> 6);
        float c = tgt[i];
        xm1[i] = c > 0.f ? c * Umax[bs] : (c < 0.f ? c * Umin[bs] : 0.f);
        xa1[i] = c * Usum[bs] * (1.f / TQN);
    } else {
        int i2 = i - BB * NKK;
        if (i2 < BB * TQN) {
            int b = i2 >> 11, q = i2 & 2047;
            float vmax = -FLT_MAX, vsum = 0.f;
#pragma unroll
            for (int s = 0; s < SS; ++s) {
                int bs = b * SS + s;
                float u = U[(size_t)bs * TQN + q];
                float pm_ = u > 0.f ? u * cmax[bs] : (u < 0.f ? u * cmin[bs] : 0.f);
                vmax = fmaxf(vmax, pm_);
                vsum += u * csum[bs];
            }
            xm2[i2] = vmax;
            xa2[i2] = vsum * (1.f / NKK);
        }
    }
}

// ---------------------------------------------------------------------------
// hidden-layer partial body, fully constexpr
// ---------------------------------------------------------------------------
template<int NH, int JT, int RC>
__device__ __forceinline__ void h_body(int b, int jt, int rc, int t,
                                       const float* __restrict__ xm,
                                       const float* __restrict__ xa,
                                       const float* __restrict__ w1,
                                       float* __restrict__ pm_, float* __restrict__ pa_,
                                       float* sxm, float* sxa) {
    int rbase = rc * 256;
    sxm[t] = xm[rbase + t];
    sxa[t] = xa[rbase + t];
    __syncthreads();
    int lane = t & 63, wv = t >> 6;
    int j = jt * 64 + lane;
    float accm = 0.f, acca = 0.f;
    if (j < NH) {
        const float* wp = w1 + (size_t)(rbase + wv * 64) * NH + j;
#pragma unroll
        for (int rr = 0; rr < 64; ++rr) {
            float w = wp[(size_t)rr * NH];
            accm += sxm[wv * 64 + rr] * w;
            acca += sxa[wv * 64 + rr] * w;
        }
    }
    __shared__ float pm[4][64], pa[4][64];
    pm[wv][lane] = accm; pa[wv][lane] = acca;
    __syncthreads();
    if (t < 64) {
        int idx = ((b * JT + jt) * RC + rc) * 64 + t;
        pm_[idx] = pm[0][t] + pm[1][t] + pm[2][t] + pm[3][t];
        pa_[idx] = pa[0][t] + pa[1][t] + pa[2][t] + pa[3][t];
    }
}

// blocks [0,64): br1 (b, jt<4, rc<4); [64,288): br2 (b, jt<7, rc<8)
__global__ __launch_bounds__(256) void k_hA(const float* __restrict__ xm1,
                                            const float* __restrict__ xa1,
                                            const float* __restrict__ xm2,
                                            const float* __restrict__ xa2,
                                            const float* __restrict__ w1a,
                                            const float* __restrict__ w1b,
                                            float* __restrict__ p1m, float* __restrict__ p1a,
                                            float* __restrict__ p2m, float* __restrict__ p2a) {
    __shared__ float sxm[256], sxa[256];
    int blk = blockIdx.x, t = threadIdx.x;
    if (blk < 64) {
        int b = blk >> 4, jt = (blk >> 2) & 3, rc = blk & 3;
        h_body<MID1, 4, 4>(b, jt, rc, t, xm1 + b * NKK, xa1 + b * NKK, w1a,
                           p1m, p1a, sxm, sxa);
    } else {
        int blk2 = blk - 64;
        int b = blk2 / 56, r_ = blk2 % 56, jt = r_ >> 3, rc = r_ & 7;
        h_body<MID2, 7, 8>(b, jt, rc, t, xm2 + b * TQN, xa2 + b * TQN, w1b,
                           p2m, p2a, sxm, sxa);
    }
}

// ---------------------------------------------------------------------------
// out-layer partial body, constexpr dims
// ---------------------------------------------------------------------------
template<int NH, int NOUT, int RT, int JC, int CHJ, int JT, int RC>
__device__ __forceinline__ void o_body(int b, int rt, int jc, int t,
                                       const float* __restrict__ pmL,
                                       const float* __restrict__ paL,
                                       const float* __restrict__ b1,
                                       const float* __restrict__ w2,
                                       float* __restrict__ qm_, float* __restrict__ qa_,
                                       float* shm, float* sha) {
    int jbase = jc * CHJ;
    if (t < CHJ) {
        int j = jbase + t;
        if (j < NH) {
            int jt_ = j >> 6, t64 = j & 63;
            float m_ = 0.f, a_ = 0.f;
#pragma unroll
            for (int rc = 0; rc < RC; ++rc) {
                int idx = ((b * JT + jt_) * RC + rc) * 64 + t64;
                m_ += pmL[idx]; a_ += paL[idx];
            }
            float bb_ = b1[j];
            shm[t] = fmaxf(m_ + bb_, 0.f);
            sha[t] = fmaxf(a_ + bb_, 0.f);
        } else { shm[t] = 0.f; sha[t] = 0.f; }
    }
    __syncthreads();
    int rl = t & 127, jp = t >> 7;
    int r = rt * 128 + rl;
    float accm = 0.f, acca = 0.f;
#pragma unroll 8
    for (int jj = jp; jj < CHJ; jj += 2) {
        int j = jbase + jj;
        int j2 = j < NH ? j : NH - 1;
        float w = w2[(size_t)j2 * NOUT + r];
        accm += shm[jj] * w; acca += sha[jj] * w;
    }
    __shared__ float qm[2][128], qa[2][128];
    qm[jp][rl] = accm; qa[jp][rl] = acca;
    __syncthreads();
    if (t < 128) {
        int idx = ((b * RT + rt) * JC + jc) * 128 + t;
        qm_[idx] = qm[0][t] + qm[1][t];
        qa_[idx] = qa[0][t] + qa[1][t];
    }
}

// blocks [0,64): br1 (b, rt<8, jc<2); [64,320): br2 (b, rt<16, jc<4)
__global__ __launch_bounds__(256) void k_oA(const float* __restrict__ p1m,
                                            const float* __restrict__ p1a,
                                            const float* __restrict__ p2m,
                                            const float* __restrict__ p2a,
                                            const float* __restrict__ b1a_,
                                            const float* __restrict__ b1b_,
                                            const float* __restrict__ w2a,
                                            const float* __restrict__ w2b,
                                            float* __restrict__ q1m, float* __restrict__ q1a,
                                            float* __restrict__ q2m, float* __restrict__ q2a) {
    __shared__ float shm[104], sha[104];
    int blk = blockIdx.x, t = threadIdx.x;
    if (blk < 64) {
        int b = blk >> 4, rt = (blk >> 1) & 7, jc = blk & 1;
        o_body<MID1, NKK, 8, 2, 102, 4, 4>(b, rt, jc, t, p1m, p1a, b1a_, w2a,
                                           q1m, q1a, shm, sha);
    } else {
        int blk2 = blk - 64;
        int b = blk2 >> 6, r_ = blk2 & 63, rt = r_ >> 2, jc = r_ & 3;
        o_body<MID2, TQN, 16, 4, 103, 7, 8>(b, rt, jc, t, p2m, p2a, b1b_, w2b,
                                            q2m, q2a, shm, sha);
    }
}

// ---------------------------------------------------------------------------
// K6: finalize out-layer + fuse MLP + softmax + 1.
// ---------------------------------------------------------------------------
__global__ __launch_bounds__(256) void k_smx(const float* __restrict__ q1m,
                                             const float* __restrict__ q1a,
                                             const float* __restrict__ q2m,
                                             const float* __restrict__ q2a,
                                             const float* __restrict__ b2a_,
                                             const float* __restrict__ b2b_,
                                             const float* __restrict__ fw1, const float* __restrict__ fb1,
                                             const float* __restrict__ fw2, const float* __restrict__ fb2,
                                             float* __restrict__ W1, float* __restrict__ W2) {
    int blk = blockIdx.x, t = threadIdx.x;
    int lane = t & 63, wv = t >> 6;
    float f0 = fw1[0], f1 = fw1[1], fb = fb1[0], g0 = fw2[0], gb = fb2[0];
    __shared__ float rb[4];

    if (blk < BB) {
        int b = blk;
        float yv[4];
#pragma unroll
        for (int k = 0; k < 4; ++k) {
            int r = t + 256 * k;
            int rt = r >> 7, rl = r & 127;
            float bb_ = b2a_[r];
            float ym = bb_, ya = bb_;
#pragma unroll
            for (int jc = 0; jc < 2; ++jc) {
                int idx = ((b * 8 + rt) * 2 + jc) * 128 + rl;
                ym += q1m[idx]; ya += q1a[idx];
            }
            float z = fmaxf(ya * f0 + ym * f1 + fb, 0.f);
            yv[k] = z * g0 + gb;
        }
        float mx = fmaxf(fmaxf(yv[0], yv[1]), fmaxf(yv[2], yv[3]));
        for (int o = 32; o; o >>= 1) mx = fmaxf(mx, __shfl_down(mx, o, 64));
        if (lane == 0) rb[wv] = mx;
        __syncthreads();
        mx = fmaxf(fmaxf(rb[0], rb[1]), fmaxf(rb[2], rb[3]));
        __syncthreads();
        float e[4], sm = 0.f;
#pragma unroll
        for (int k = 0; k < 4; ++k) { e[k] = expf(yv[k] - mx); sm += e[k]; }
        for (int o = 32; o; o >>= 1) sm += __shfl_down(sm, o, 64);
        if (lane == 0) rb[wv] = sm;
        __syncthreads();
        sm = rb[0] + rb[1] + rb[2] + rb[3];
        float inv = 1.f / sm;
#pragma unroll
        for (int k = 0; k < 4; ++k)
            W1[b * NKK + t + 256 * k] = e[k] * inv + 1.f;
    } else {
        int b = blk - BB;
        float yv[8];
#pragma unroll
        for (int k = 0; k < 8; ++k) {
            int r = t + 256 * k;
            int rt = r >> 7, rl = r & 127;
            float bb_ = b2b_[r];
            float ym = bb_, ya = bb_;
#pragma unroll
            for (int jc = 0; jc < 4; ++jc) {
                int idx = ((b * 16 + rt) * 4 + jc) * 128 + rl;
                ym += q2m[idx]; ya += q2a[idx];
            }
            float z = fmaxf(ya * f0 + ym * f1 + fb, 0.f);
            yv[k] = z * g0 + gb;
        }
        float mx = yv[0];
#pragma unroll
        for (int k = 1; k < 8; ++k) mx = fmaxf(mx, yv[k]);
        for (int o = 32; o; o >>= 1) mx = fmaxf(mx, __shfl_down(mx, o, 64));
        if (lane == 0) rb[wv] = mx;
        __syncthreads();
        mx = fmaxf(fmaxf(rb[0], rb[1]), fmaxf(rb[2], rb[3]));
        __syncthreads();
        float e[8], sm = 0.f;
#pragma unroll
        for (int k = 0; k < 8; ++k) { e[k] = expf(yv[k] - mx); sm += e[k]; }
        for (int o = 32; o; o >>= 1) sm += __shfl_down(sm, o, 64);
        if (lane == 0) rb[wv] = sm;
        __syncthreads();
        sm = rb[0] + rb[1] + rb[2] + rb[3];
        float inv = 1.f / sm;
#pragma unroll
        for (int k = 0; k < 8; ++k) W2[b * TQN + t + 256 * k] = e[k] * inv + 1.f;
    }
}

// ---------------------------------------------------------------------------
// K7: proto output + c2[b,s,n]
// ---------------------------------------------------------------------------
__global__ __launch_bounds__(256) void k_proto(const float* __restrict__ W1,
                                               const float* __restrict__ tgt,
                                               const float* __restrict__ sup,
                                               float* __restrict__ proto,
                                               float* __restrict__ c2) {
    int bn = blockIdx.x;
    int b = bn >> 6, n = bn & 63;
    int t = threadIdx.x;
    float a0 = 0.f, a1 = 0.f, a2 = 0.f, cnt = 0.f;
#pragma unroll
    for (int s = 0; s < SS; ++s) {
        float tg = tgt[((size_t)b * SS + s) * NTT + n];
        float coef = W1[b * NKK + s * NTT + n] * tg;
        const float* sv = sup + ((size_t)b * SS + s) * DD;
        a0 += coef * sv[t];
        a1 += coef * sv[t + 256];
        a2 += coef * sv[t + 512];
        cnt += tg;
    }
    float inv = 1.f / (cnt + 1e-4f);
    float* p = proto + (size_t)bn * DD;
    p[t] = a0 * inv; p[t + 256] = a1 * inv; p[t + 512] = a2 * inv;
    if (t < SS) {
        float tg = tgt[((size_t)b * SS + t) * NTT + n];
        c2[((size_t)b * SS + t) * NTT + n] = W1[b * NKK + t * NTT + n] * tg * inv;
    }
}

// ---------------------------------------------------------------------------
// K8: sim[b,q,n] = W2[b,q] * sum_s U[b,s,q] * c2[b,s,n]
// ---------------------------------------------------------------------------
__global__ __launch_bounds__(256) void k_simU(const float* __restrict__ U,
                                              const float* __restrict__ c2,
                                              const float* __restrict__ W2,
                                              float* __restrict__ sim) {
    int blk = blockIdx.x;
    int b = blk >> 3, q0 = (blk & 7) * 256;
    int t = threadIdx.x;
    __shared__ float sc[SS][NTT];
    for (int i = t; i < SS * NTT; i += 256)
        sc[i >> 6][i & 63] = c2[(size_t)b * SS * NTT + i];
    __syncthreads();
    int q = q0 + t;
    float u[SS];
#pragma unroll
    for (int s = 0; s < SS; ++s)
        u[s] = U[((size_t)b * SS + s) * TQN + q];
    float w = W2[b * TQN + q];
    float* simp = sim + ((size_t)b * TQN + q) * NTT;
#pragma unroll 4
    for (int n4 = 0; n4 < NTT / 4; ++n4) {
        float4 o;
        float a0 = 0.f, a1 = 0.f, a2 = 0.f, a3 = 0.f;
#pragma unroll
        for (int s = 0; s < SS; ++s) {
            float us = u[s];
            a0 += us * sc[s][n4 * 4 + 0];
            a1 += us * sc[s][n4 * 4 + 1];
            a2 += us * sc[s][n4 * 4 + 2];
            a3 += us * sc[s][n4 * 4 + 3];
        }
        o.x = a0 * w; o.y = a1 * w; o.z = a2 * w; o.w = a3 * w;
        *reinterpret_cast<float4*>(&simp[n4 * 4]) = o;
    }
}

// ---------------------------------------------------------------------------
extern "C" void kernel_launch(void* const* d_in, const int* in_sizes, int n_in,
                              void* d_out, int out_size, void* d_ws, size_t ws_size,
                              hipStream_t stream) {
    const float* reps = (const float*)d_in[0];
    const float* sup  = (const float*)d_in[1];
    const float* tgt  = (const float*)d_in[4];
    const float* l1w1 = (const float*)d_in[5];
    const float* l1b1 = (const float*)d_in[6];
    const float* l1w2 = (const float*)d_in[7];
    const float* l1b2 = (const float*)d_in[8];
    const float* l2w1 = (const float*)d_in[9];
    const float* l2b1 = (const float*)d_in[10];
    const float* l2w2 = (const float*)d_in[11];
    const float* l2b2 = (const float*)d_in[12];
    const float* fw1  = (const float*)d_in[13];
    const float* fb1  = (const float*)d_in[14];
    const float* fw2  = (const float*)d_in[15];
    const float* fb2  = (const float*)d_in[16];

    float* out    = (float*)d_out;
    float* simO   = out;
    float* protoO = out + (size_t)BB * TQN * NTT;

    float* w = (float*)d_ws;
    float* U     = w; w += (size_t)BB * SS * TQN;
    float* Umax  = w; w += 64;
    float* Umin  = w; w += 64;
    float* Usum  = w; w += 64;
    float* cmaxp = w; w += 64;
    float* cminp = w; w += 64;
    float* csump = w; w += 64;
    float* xm1   = w; w += BB * NKK;
    float* xa1   = w; w += BB * NKK;
    float* xm2   = w; w += BB * TQN;
    float* xa2   = w; w += BB * TQN;
    float* p1m   = w; w += BB * 4 * 4 * 64;
    float* p1a   = w; w += BB * 4 * 4 * 64;
    float* p2m   = w; w += BB * 7 * 8 * 64;
    float* p2a   = w; w += BB * 7 * 8 * 64;
    float* q1m   = w; w += BB * 8 * 2 * 128;
    float* q1a   = w; w += BB * 8 * 2 * 128;
    float* q2m   = w; w += BB * 16 * 4 * 128;
    float* q2a   = w; w += BB * 16 * 4 * 128;
    float* W1    = w; w += BB * NKK;
    float* W2    = w; w += BB * TQN;
    float* c2    = w; w += BB * SS * NTT;

    k_mean_u<<<BB * (TQN / 8), 256, 0, stream>>>((const nt_f4*)reps,
                                                 (const float4*)sup, U);
    k_stats<<<BB * SS, 256, 0, stream>>>(U, tgt, Umax, Umin, Usum, cmaxp, cminp, csump);
    k_feat<<<(BB * NKK + BB * TQN) / 256, 256, 0, stream>>>(tgt, Umax, Umin, Usum,
                                                            U, cmaxp, cminp, csump,
                                                            xm1, xa1, xm2, xa2);
    k_hA<<<64 + 224, 256, 0, stream>>>(xm1, xa1, xm2, xa2, l1w1, l2w1,
                                       p1m, p1a, p2m, p2a);
    k_oA<<<64 + 256, 256, 0, stream>>>(p1m, p1a, p2m, p2a, l1b1, l2b1,
                                       l1w2, l2w2, q1m, q1a, q2m, q2a);
    k_smx<<<2 * BB, 256, 0, stream>>>(q1m, q1a, q2m, q2a, l1b2, l2b2,
                                      fw1, fb1, fw2, fb2, W1, W2);
    k_proto<<<BB * NTT, 256, 0, stream>>>(W1, tgt, sup, protoO, c2);
    k_simU<<<BB * (TQN / 256), 256, 0, stream>>>(U, c2, W2, simO);
}